// Round 7
// baseline (131.754 us; speedup 1.0000x reference)
//
#include <hip/hip_runtime.h>
#include <hip/hip_bf16.h>

#define N_NODES 50000
#define E_EDGES 800000
#define IN_DIM  128
#define OUT_DIM 64
#define MTILES  (N_NODES / 16)   // 3125, exact
#define NB      196              // coarse dst buckets (dst >> 8)
#define BCAP    6144             // bucket capacity: mean 4096, sd 64 -> +32 sigma
#define OVF_CAP 16384            // overflow list (expected use: 0)
#define NBLK_FC 782              // ceil(3125/4) fc blocks (4 tiles each)
#define NBLK_SA 625              // pass-A blocks
#define EPA     1280             // 800000/625 edges per pass-A block
#define ITER_A  5                // EPA / 256, uniform compile-time trip count
#define NSPLIT  4                // bucket split for merged sort+gather
#define PART    64               // nodes per split part (256/NSPLIT)
#define ES_CAP  3072             // per-part edge cap: mean 1024, sd 32 -> +64 sigma

static_assert(N_NODES % 16 == 0, "16-row MFMA tiles");
static_assert(N_NODES < 65536, "node ids packed in 16 bits");
static_assert(NBLK_SA * EPA == E_EDGES, "pass-A blocks partition edges");
static_assert(EPA == ITER_A * 256, "uniform per-thread trip count");
static_assert(NB * 256 >= N_NODES, "buckets cover dst space");
static_assert(NSPLIT * PART == 256, "parts tile a bucket");

// ws: harness provides 256 MB; this layout uses ~11.7 MB.

typedef __attribute__((ext_vector_type(8))) short bf16x8;
typedef __attribute__((ext_vector_type(4))) float f32x4;
typedef __attribute__((ext_vector_type(8))) unsigned short u16x8;

__device__ __forceinline__ unsigned short f32_to_bf16_rne(float f) {
    unsigned u = __float_as_uint(f);
    return (unsigned short)((u + 0x7FFFu + ((u >> 16) & 1u)) >> 16);
}
__device__ __forceinline__ float bf16_to_f32(unsigned short s) {
    return __uint_as_float(((unsigned)s) << 16);
}

// ---------------------------------------------------------------------------
// K1 (fused): blocks [0, NBLK_SA) = pass A (FIRST, so the slower sort blocks
// start early and their tail overlaps the fc blocks); [NBLK_SA, +NBLK_FC) =
// MFMA fc. Pass A: 1280 edges/block, operands hoisted, bucket-sorted in LDS,
// wave-shfl scan, coalesced copy-out.
// ---------------------------------------------------------------------------
__global__ __launch_bounds__(256) void gat_fc_scatter(
    const float* __restrict__ h,
    const float* __restrict__ Wfc,
    const float* __restrict__ bfc,
    const float* __restrict__ Watt,
    const float* __restrict__ batt,
    const int*   __restrict__ adj,
    unsigned short* __restrict__ z16,
    float* __restrict__ s1,
    float* __restrict__ s2,
    int*      __restrict__ gcnt,      // [NB+1] pre-zeroed; [NB] = ovf count
    unsigned* __restrict__ coarse,    // [NB*BCAP]
    unsigned* __restrict__ ovf)
{
    __shared__ short Wlds[OUT_DIM][IN_DIM + 8];   // 17.4 KB (fc blocks)

    if (blockIdx.x >= NBLK_SA) {
        // ------------------------------ fc ------------------------------
        for (int i = threadIdx.x; i < OUT_DIM * IN_DIM; i += 256) {
            const int o = i >> 7;            // /128
            const int k = i & 127;
            Wlds[o][k] = (short)f32_to_bf16_rne(Wfc[i]);
        }
        __syncthreads();

        const int lane  = threadIdx.x & 63;
        const int c     = lane & 15;          // A row / B col / C col
        const int q     = lane >> 4;          // quad
        const int mtile = (blockIdx.x - NBLK_SA) * 4 + (threadIdx.x >> 6);
        if (mtile >= MTILES) return;
        const int n0 = mtile * 16;

        // B fragments: B[k=t*32+q*8+j][n=f*16+c] = W[f*16+c][t*32+q*8+j]
        bf16x8 B[4][4];
        #pragma unroll
        for (int t = 0; t < 4; ++t)
            #pragma unroll
            for (int f = 0; f < 4; ++f)
                B[t][f] = *(const bf16x8*)&Wlds[f * 16 + c][t * 32 + q * 8];

        f32x4 acc[4] = {{0,0,0,0},{0,0,0,0},{0,0,0,0},{0,0,0,0}};

        const float* arow = h + (size_t)(n0 + c) * IN_DIM + q * 8;
        #pragma unroll
        for (int t = 0; t < 4; ++t) {
            float4 x0 = *(const float4*)(arow + t * 32);
            float4 x1 = *(const float4*)(arow + t * 32 + 4);
            bf16x8 a;
            a[0] = (short)f32_to_bf16_rne(x0.x);
            a[1] = (short)f32_to_bf16_rne(x0.y);
            a[2] = (short)f32_to_bf16_rne(x0.z);
            a[3] = (short)f32_to_bf16_rne(x0.w);
            a[4] = (short)f32_to_bf16_rne(x1.x);
            a[5] = (short)f32_to_bf16_rne(x1.y);
            a[6] = (short)f32_to_bf16_rne(x1.z);
            a[7] = (short)f32_to_bf16_rne(x1.w);
            #pragma unroll
            for (int f = 0; f < 4; ++f)
                acc[f] = __builtin_amdgcn_mfma_f32_16x16x32_bf16(a, B[t][f], acc[f], 0, 0, 0);
        }

        const float batt0 = batt[0];
        float w1c[4], w2c[4], bv[4];
        #pragma unroll
        for (int f = 0; f < 4; ++f) {
            w1c[f] = Watt[f * 16 + c];
            w2c[f] = Watt[OUT_DIM + f * 16 + c];
            bv[f]  = bfc[f * 16 + c];
        }
        float p1[4] = {0,0,0,0}, p2[4] = {0,0,0,0};
        #pragma unroll
        for (int f = 0; f < 4; ++f)
            #pragma unroll
            for (int r = 0; r < 4; ++r) {
                const float v = acc[f][r] + bv[f];
                z16[(size_t)(n0 + q * 4 + r) * OUT_DIM + f * 16 + c] = f32_to_bf16_rne(v);
                p1[r] += v * w1c[f];
                p2[r] += v * w2c[f];
            }
        #pragma unroll
        for (int r = 0; r < 4; ++r) {
            #pragma unroll
            for (int off = 1; off < 16; off <<= 1) {
                p1[r] += __shfl_xor(p1[r], off, 64);
                p2[r] += __shfl_xor(p2[r], off, 64);
            }
            if (c == 0) {
                s1[n0 + q * 4 + r] = p1[r];
                s2[n0 + q * 4 + r] = p2[r] + batt0;   // fold b_att in
            }
        }
    } else {
        // --------------------------- pass A -----------------------------
        __shared__ unsigned el[EPA];                  // 5.1 KB, bucket-sorted
        __shared__ int sof[256];                      // histogram
        __shared__ int bexc[NB], lcur[NB], gbase[NB]; // 2.4 KB
        __shared__ int wsum[4];

        const int k    = blockIdx.x;                  // 0..624
        const int e0   = k * EPA;
        const int t    = threadIdx.x;
        const int lane = t & 63;
        const int w    = t >> 6;

        sof[t] = 0;
        __syncthreads();

        // 0) hoist this thread's 5 dst+src pairs into registers
        unsigned dv[ITER_A], sv[ITER_A];
        #pragma unroll
        for (int it = 0; it < ITER_A; ++it) {
            dv[it] = (unsigned)adj[E_EDGES + e0 + t + it * 256];
            sv[it] = (unsigned)adj[e0 + t + it * 256];
        }

        // 1) LDS histogram of this block's 1280 dsts
        #pragma unroll
        for (int it = 0; it < ITER_A; ++it)
            atomicAdd(&sof[dv[it] >> 8], 1);
        __syncthreads();

        // 2) wave-shfl exclusive scan (2 barriers)
        const int v = sof[t];
        int x = v;
        #pragma unroll
        for (int off = 1; off < 64; off <<= 1) {
            const int y = __shfl_up(x, off, 64);
            if (lane >= off) x += y;
        }
        if (lane == 63) wsum[w] = x;
        __syncthreads();
        int prefix = 0;
        #pragma unroll
        for (int ww = 0; ww < 4; ++ww)
            if (ww < w) prefix += wsum[ww];
        const int excl = x + prefix - v;
        if (t < NB) {
            bexc[t]  = excl;
            lcur[t]  = excl;
            gbase[t] = atomicAdd(&gcnt[t], v);   // 196 global atomics/block
        }
        __syncthreads();

        // 3) place edges bucket-sorted into LDS
        #pragma unroll
        for (int it = 0; it < ITER_A; ++it) {
            const int b = (int)(dv[it] >> 8);
            const int p = atomicAdd(&lcur[b], 1);
            el[p] = (dv[it] << 16) | sv[it];
        }
        __syncthreads();

        // 4) coalesced copy-out
        #pragma unroll
        for (int it = 0; it < ITER_A; ++it) {
            const int i = t + it * 256;
            const unsigned packed = el[i];
            const int b = (int)(packed >> 24);           // dst>>8
            const int pin = gbase[b] + (i - bexc[b]);
            if (pin < BCAP) {
                coarse[(size_t)b * BCAP + pin] = packed;
            } else {
                const int o = atomicAdd(&gcnt[NB], 1);
                if (o < OVF_CAP) ovf[o] = packed;
            }
        }
    }
}

// ---------------------------------------------------------------------------
// K2 (merged sort+gather, 4-way bucket split): grid = NB*4 blocks x 512 thr
// (~3 blocks/CU, 24 waves/CU -- fixes round-2's 196-block under-utilization).
// Block (b,p) owns nodes b*256+p*64 .. +63. Two passes over the bucket's
// unsorted edges (count, then place into a 12 KB LDS es[]), 64-bin wave-0
// scan, then the validated 8-lane x 8-slot gather from LDS, 8 nodes/wave.
// Kills: sorted write-back (3.2 MB), csrt re-read, start/deg round-trips,
// and one kernel launch.
// ---------------------------------------------------------------------------
__global__ __launch_bounds__(512) void gat_sort_gather(
    const unsigned* __restrict__ coarse,
    const int* __restrict__ gcnt,
    const unsigned* __restrict__ ovf,
    const float* __restrict__ s1, const float* __restrict__ s2,
    const unsigned short* __restrict__ z16,
    float* __restrict__ out)
{
    __shared__ unsigned es[ES_CAP];               // 12 KB dst-sorted slice
    __shared__ int hist[PART], sof[PART], cur[PART];
    const int B  = blockIdx.x;
    const int b  = B >> 2;
    const int p  = B & 3;
    const int t  = threadIdx.x;
    const int nb = min(gcnt[b], BCAP);
    const unsigned lnlo = (unsigned)(p * PART);

    if (t < PART) hist[t] = 0;
    __syncthreads();

    // pass 1: count this part's nodes (coalesced bucket read)
    for (int i = t; i < nb; i += 512) {
        const unsigned ln = (coarse[(size_t)b * BCAP + i] >> 16) & 255u;
        if ((ln >> 6) == (unsigned)p) atomicAdd(&hist[ln - lnlo], 1);
    }
    __syncthreads();

    // 64-bin exclusive scan in wave 0
    if (t < 64) {
        const int v = hist[t];
        int x = v;
        #pragma unroll
        for (int off = 1; off < 64; off <<= 1) {
            const int y = __shfl_up(x, off, 64);
            if ((t & 63) >= off) x += y;
        }
        sof[t] = x - v;
        cur[t] = x - v;
    }
    __syncthreads();

    // pass 2: place (re-read from L2; scatter stays in LDS)
    for (int i = t; i < nb; i += 512) {
        const unsigned e  = coarse[(size_t)b * BCAP + i];
        const unsigned ln = (e >> 16) & 255u;
        if ((ln >> 6) == (unsigned)p) {
            const int pos = atomicAdd(&cur[ln - lnlo], 1);
            if (pos < ES_CAP) es[pos] = e;   // cap = +64 sigma, never hit
        }
    }
    __syncthreads();

    // ---------------- gather: 8 waves x 8 nodes ----------------
    const int lane = t & 63;
    const int c    = lane & 7;        // feature group: features 8c..8c+7
    const int q    = lane >> 3;       // edge slot 0..7
    const int w    = t >> 6;          // wave id 0..7
    const int novf = min(gcnt[NB], OVF_CAP);

    for (int ii = 0; ii < 8; ++ii) {
        const int l = w * 8 + ii;               // local node, wave-uniform
        const int n = b * 256 + p * PART + l;
        if (n >= N_NODES) continue;             // wave-uniform branch

        const int m  = hist[l];
        const int jb = sof[l];
        const float s2n = s2[n];                // includes b_att

        float acc[8] = {0,0,0,0,0,0,0,0};
        int j = 0;
        for (; j + 16 <= m; j += 16) {
            const int srcA = (int)(es[jb + j + q] & 0xFFFFu);
            const int srcB = (int)(es[jb + j + 8 + q] & 0xFFFFu);
            float aA = s1[srcA] + s2n;
            float aB = s1[srcB] + s2n;
            aA = (aA > 0.f) ? aA : 0.01f * aA;
            aB = (aB > 0.f) ? aB : 0.01f * aB;
            const u16x8 zA = *(const u16x8*)&z16[(size_t)srcA * OUT_DIM + 8 * c];
            const u16x8 zB = *(const u16x8*)&z16[(size_t)srcB * OUT_DIM + 8 * c];
            #pragma unroll
            for (int u = 0; u < 8; ++u) acc[u] += aA * bf16_to_f32(zA[u]);
            #pragma unroll
            for (int u = 0; u < 8; ++u) acc[u] += aB * bf16_to_f32(zB[u]);
        }
        for (; j + 8 <= m; j += 8) {
            const int src = (int)(es[jb + j + q] & 0xFFFFu);
            float a = s1[src] + s2n;
            a = (a > 0.f) ? a : 0.01f * a;
            const u16x8 zz = *(const u16x8*)&z16[(size_t)src * OUT_DIM + 8 * c];
            #pragma unroll
            for (int u = 0; u < 8; ++u) acc[u] += a * bf16_to_f32(zz[u]);
        }
        if (q < m - j) {
            const int src = (int)(es[jb + j + q] & 0xFFFFu);
            float a = s1[src] + s2n;
            a = (a > 0.f) ? a : 0.01f * a;
            const u16x8 zz = *(const u16x8*)&z16[(size_t)src * OUT_DIM + 8 * c];
            #pragma unroll
            for (int u = 0; u < 8; ++u) acc[u] += a * bf16_to_f32(zz[u]);
        }

        // self-service overflow (expected 0)
        for (int base = 0; base < novf; base += 8) {
            const int idx = base + q;
            const unsigned packed = (idx < novf) ? ovf[idx] : 0xFFFFFFFFu;
            const bool valid = (idx < novf) && ((packed >> 16) == (unsigned)n);
            const int src = valid ? (int)(packed & 0xFFFFu) : 0;
            float a = s1[src] + s2n;
            a = (a > 0.f) ? a : 0.01f * a;
            a = valid ? a : 0.f;
            const u16x8 zz = *(const u16x8*)&z16[(size_t)src * OUT_DIM + 8 * c];
            #pragma unroll
            for (int u = 0; u < 8; ++u) acc[u] += a * bf16_to_f32(zz[u]);
        }

        // combine the 8 edge slots (slot index in lane bits 3..5)
        #pragma unroll
        for (int u = 0; u < 8; ++u) {
            acc[u] += __shfl_xor(acc[u], 8, 64);
            acc[u] += __shfl_xor(acc[u], 16, 64);
            acc[u] += __shfl_xor(acc[u], 32, 64);
        }

        if (q == 0) {
            float4 lo = make_float4(acc[0], acc[1], acc[2], acc[3]);
            float4 hi = make_float4(acc[4], acc[5], acc[6], acc[7]);
            *(float4*)&out[(size_t)n * OUT_DIM + 8 * c]     = lo;
            *(float4*)&out[(size_t)n * OUT_DIM + 8 * c + 4] = hi;
        }
    }
}

extern "C" void kernel_launch(void* const* d_in, const int* in_sizes, int n_in,
                              void* d_out, int out_size, void* d_ws, size_t ws_size,
                              hipStream_t stream)
{
    const int*   adj  = (const int*)  d_in[0];   // (2, E)
    const float* h    = (const float*)d_in[1];   // (N, 128)
    const float* Wfc  = (const float*)d_in[2];   // (64, 128)
    const float* bfc  = (const float*)d_in[3];   // (64,)
    const float* Watt = (const float*)d_in[4];   // (1, 128)
    const float* batt = (const float*)d_in[5];   // (1,)
    float* out = (float*)d_out;                  // (N, 64)

    // ws layout (~11.7 MB): z16[N*64] u16 | s1[N] | s2[N]
    // | gcnt[NB+1] ([NB]=ovf count) | ovf[OVF_CAP] u32 | coarse[NB*BCAP] u32
    unsigned short* z16 = (unsigned short*)d_ws;
    float* s1    = (float*)(z16 + (size_t)N_NODES * OUT_DIM);
    float* s2    = s1 + N_NODES;
    int*   gcnt  = (int*)(s2 + N_NODES);
    unsigned* ovf    = (unsigned*)(gcnt + NB + 1);
    unsigned* coarse = ovf + OVF_CAP;

    hipMemsetAsync(gcnt, 0, (NB + 1) * sizeof(int), stream);

    gat_fc_scatter<<<NBLK_FC + NBLK_SA, 256, 0, stream>>>(
        h, Wfc, bfc, Watt, batt, adj, z16, s1, s2, gcnt, coarse, ovf);
    gat_sort_gather<<<NB * NSPLIT, 512, 0, stream>>>(
        coarse, gcnt, ovf, s1, s2, z16, out);
}